// Round 1
// 10402.645 us; speedup vs baseline: 1.5676x; 1.5676x over previous
//
#include <hip/hip_runtime.h>
#include <math.h>

// Model dims
#define NBLK 6
#define BS   200
#define NHID 1200
#define NINP 2400
#define TT   32
#define BZ   32
#define NTOK 16000
#define NG   4800      // NBLK*4*BS
#define ROWS 1024      // TT*BZ
#define L1D  1600      // 8 heads * 200

__device__ __forceinline__ float sigmoidf_(float x) { return 1.0f / (1.0f + expf(-x)); }

// ---------------------------------------------------------------------------
// 128x128-tile fp32 GEMM, 8x8 per thread. C[M,N] = A[M,K] @ B (+bias1+bias2)
// BT=false: B is (K,N) row-major. BT=true: B is (N,K) row-major.
// a_idx: optional row gather. Requires M % 128 == 0, K % 8 == 0, N % 4 == 0.
// ---------------------------------------------------------------------------
template <bool BT>
__global__ __launch_bounds__(256) void gemm128_kernel(
    const float* __restrict__ A, const float* __restrict__ B,
    const float* __restrict__ bias1, const float* __restrict__ bias2,
    float* __restrict__ C, int M, int N, int K, const int* __restrict__ a_idx)
{
    __shared__ __align__(16) float As[8][132];
    __shared__ __align__(16) float Bs[8][132];
    const int tid = threadIdx.x;
    const int tx = tid & 15, ty = tid >> 4;
    const int n0 = blockIdx.x * 128, m0 = blockIdx.y * 128;

    const int la_r = tid >> 1, la_k = (tid & 1) * 4;
    long arow;
    {
        int row = m0 + la_r;
        arow = a_idx ? (long)a_idx[row] * K : (long)row * K;
    }
    float acc[8][8] = {};

    for (int k0 = 0; k0 < K; k0 += 8) {
        {
            float4 v = *(const float4*)&A[arow + k0 + la_k];
            As[la_k + 0][la_r] = v.x;
            As[la_k + 1][la_r] = v.y;
            As[la_k + 2][la_r] = v.z;
            As[la_k + 3][la_r] = v.w;
        }
        if constexpr (!BT) {
            int kk = tid >> 5, n = (tid & 31) * 4;
            int col = n0 + n;
            float4 v = make_float4(0.f, 0.f, 0.f, 0.f);
            if (col < N) v = *(const float4*)&B[(long)(k0 + kk) * N + col];
            *(float4*)&Bs[kk][n] = v;
        } else {
            int n = tid >> 1, kk0 = (tid & 1) * 4;
            int col = n0 + n;
            float4 v = make_float4(0.f, 0.f, 0.f, 0.f);
            if (col < N) v = *(const float4*)&B[(long)col * K + k0 + kk0];
            Bs[kk0 + 0][n] = v.x;
            Bs[kk0 + 1][n] = v.y;
            Bs[kk0 + 2][n] = v.z;
            Bs[kk0 + 3][n] = v.w;
        }
        __syncthreads();
        #pragma unroll
        for (int kk = 0; kk < 8; kk++) {
            float av[8], bv[8];
            *(float4*)&av[0] = *(const float4*)&As[kk][ty * 4];
            *(float4*)&av[4] = *(const float4*)&As[kk][ty * 4 + 64];
            *(float4*)&bv[0] = *(const float4*)&Bs[kk][tx * 4];
            *(float4*)&bv[4] = *(const float4*)&Bs[kk][tx * 4 + 64];
            #pragma unroll
            for (int i = 0; i < 8; i++)
                #pragma unroll
                for (int j = 0; j < 8; j++) acc[i][j] += av[i] * bv[j];
        }
        __syncthreads();
    }
    #pragma unroll
    for (int i = 0; i < 8; i++) {
        int row = m0 + ty * 4 + (i & 3) + (i >> 2) * 64;
        #pragma unroll
        for (int jg = 0; jg < 2; jg++) {
            int col = n0 + tx * 4 + jg * 64;
            if (col < N) {
                float4 v;
                v.x = acc[i][jg * 4 + 0]; v.y = acc[i][jg * 4 + 1];
                v.z = acc[i][jg * 4 + 2]; v.w = acc[i][jg * 4 + 3];
                if (bias1) {
                    float4 b1 = *(const float4*)&bias1[col];
                    v.x += b1.x; v.y += b1.y; v.z += b1.z; v.w += b1.w;
                }
                if (bias2) {
                    float4 b2 = *(const float4*)&bias2[col];
                    v.x += b2.x; v.y += b2.y; v.z += b2.z; v.w += b2.w;
                }
                *(float4*)&C[(long)row * N + col] = v;
            }
        }
    }
}

// ---------------------------------------------------------------------------
// Split-K 64x64 GEMM (B row-major K x N), writes partials Cp[z][M][N].
// grid (ceil(N/64), M/64, KS). K-range per z: [z*KL, z*KL+KL). M%64==0, KL%8==0.
// ---------------------------------------------------------------------------
__global__ __launch_bounds__(256) void gemm_skp_kernel(
    const float* __restrict__ A, const float* __restrict__ B,
    float* __restrict__ Cp, int M, int N, int K, int KL)
{
    __shared__ __align__(16) float As[8][68];
    __shared__ __align__(16) float Bs[8][68];
    const int tid = threadIdx.x;
    const int tx = tid & 15, ty = tid >> 4;
    const int n0 = blockIdx.x * 64, m0 = blockIdx.y * 64;
    const int z = blockIdx.z;
    const int kbeg = z * KL, kend = kbeg + KL;

    float acc[4][4] = {};

    for (int k0 = kbeg; k0 < kend; k0 += 8) {
        {
            int idx = tid * 2;
            int mm = idx >> 3, kk = idx & 7;
            int row = m0 + mm;
            float2 v = *(const float2*)&A[(long)row * K + k0 + kk];
            As[kk][mm] = v.x;
            As[kk + 1][mm] = v.y;
        }
        {
            int idx = tid * 2;
            int nn = idx & 63, kk = idx >> 6;
            int n = n0 + nn;
            float2 v = make_float2(0.f, 0.f);
            if (n < N) v = *(const float2*)&B[(long)(k0 + kk) * N + n];
            Bs[kk][nn] = v.x;
            Bs[kk][nn + 1] = v.y;
        }
        __syncthreads();
        #pragma unroll
        for (int kk = 0; kk < 8; kk++) {
            const float4 a4 = *(const float4*)&As[kk][ty * 4];
            const float4 b4 = *(const float4*)&Bs[kk][tx * 4];
            const float av[4] = {a4.x, a4.y, a4.z, a4.w};
            const float bv[4] = {b4.x, b4.y, b4.z, b4.w};
            #pragma unroll
            for (int i = 0; i < 4; i++)
                #pragma unroll
                for (int j = 0; j < 4; j++) acc[i][j] += av[i] * bv[j];
        }
        __syncthreads();
    }
    float* Cz = Cp + (long)z * M * N;
    #pragma unroll
    for (int i = 0; i < 4; i++) {
        int row = m0 + ty * 4 + i;
        #pragma unroll
        for (int j = 0; j < 4; j++) {
            int col = n0 + tx * 4 + j;
            if (col < N) Cz[(long)row * N + col] = acc[i][j];
        }
    }
}

// ---------------------------------------------------------------------------
// BigB[c'][h*200+c] = sum_d lq[c, h*200+d] * lk[c', h*200+d]   (200 x 1600)
// grid 1250 x 256 = 320000 outputs.
// ---------------------------------------------------------------------------
__global__ __launch_bounds__(256) void bigb_kernel(
    const float* __restrict__ lq, const float* __restrict__ lk,
    float* __restrict__ BigB)
{
    int id = blockIdx.x * 256 + threadIdx.x;
    if (id >= 320000) return;
    int h = id / 40000, r = id % 40000, cp = r / 200, c = r % 200;
    const float4* a = (const float4*)(lq + (long)c * L1D + h * 200);
    const float4* b = (const float4*)(lk + (long)cp * L1D + h * 200);
    float s0 = 0, s1 = 0, s2 = 0, s3 = 0;
    #pragma unroll 5
    for (int d = 0; d < 50; d++) {
        float4 av = a[d], bv = b[d];
        s0 += av.x * bv.x; s1 += av.y * bv.y; s2 += av.z * bv.z; s3 += av.w * bv.w;
    }
    BigB[(long)cp * L1D + h * 200 + c] = s0 + s1 + s2 + s3;
}

// ---------------------------------------------------------------------------
// Layer-0 LSTM step: gates = GX(t rows) + h@Wh^T. grid (25, 6), 256 thr.
// ---------------------------------------------------------------------------
__global__ __launch_bounds__(256) void lstm0_kernel(
    const float* __restrict__ GX,    // (32, 4800)
    const float* __restrict__ hprev, // (32, 1200)
    float* __restrict__ c_io,        // (32, 1200) in/out
    const float* __restrict__ Wh,    // (6, 800, 200)
    float* __restrict__ h_out)       // (32, 1200) pre-attention
{
    __shared__ float h_s[200 * 33];
    const int k = blockIdx.y, jt = blockIdx.x, tid = threadIdx.x;
    for (int idx = tid; idx < 1600; idx += 256) {
        int bb = idx / 50, m4 = idx % 50;
        float4 v = *(const float4*)&hprev[bb * NHID + k * BS + m4 * 4];
        h_s[(m4 * 4 + 0) * 33 + bb] = v.x;
        h_s[(m4 * 4 + 1) * 33 + bb] = v.y;
        h_s[(m4 * 4 + 2) * 33 + bb] = v.z;
        h_s[(m4 * 4 + 3) * 33 + bb] = v.w;
    }
    __syncthreads();
    const int b = tid & 31, jj = tid >> 5;
    const int j = jt * 8 + jj;
    const float* w0 = Wh + (long)(k * 800 + j) * 200;
    const float* w1 = w0 + 200 * 200;
    const float* w2 = w0 + 400 * 200;
    const float* w3 = w0 + 600 * 200;
    float a0 = 0, a1 = 0, a2 = 0, a3 = 0;
    for (int m = 0; m < 200; m += 4) {
        float4 wv0 = *(const float4*)&w0[m];
        float4 wv1 = *(const float4*)&w1[m];
        float4 wv2 = *(const float4*)&w2[m];
        float4 wv3 = *(const float4*)&w3[m];
        float h0v = h_s[(m + 0) * 33 + b];
        float h1v = h_s[(m + 1) * 33 + b];
        float h2v = h_s[(m + 2) * 33 + b];
        float h3v = h_s[(m + 3) * 33 + b];
        a0 += h0v * wv0.x + h1v * wv0.y + h2v * wv0.z + h3v * wv0.w;
        a1 += h0v * wv1.x + h1v * wv1.y + h2v * wv1.z + h3v * wv1.w;
        a2 += h0v * wv2.x + h1v * wv2.y + h2v * wv2.z + h3v * wv2.w;
        a3 += h0v * wv3.x + h1v * wv3.y + h2v * wv3.z + h3v * wv3.w;
    }
    const float* gx = GX + b * NG + k * 800;
    float gi = a0 + gx[j];
    float gf = a1 + gx[200 + j];
    float gg = a2 + gx[400 + j];
    float go = a3 + gx[600 + j];
    int o = b * NHID + k * BS + j;
    float cold = c_io[o];
    float cn = sigmoidf_(gf) * cold + sigmoidf_(gi) * tanhf(gg);
    float hn = sigmoidf_(go) * tanhf(cn);
    c_io[o] = cn;
    h_out[o] = hn;
}

// ---------------------------------------------------------------------------
// Layer-1 LSTM step: gates = inp@Wi^T + h@Wh^T + bih + bhh.
// grid (50, 6), 512 thr = (b 0..31, jg 0..3, kh 0..3). K quartered across kh,
// double-buffered x staging, LDS partial reduce.
// ---------------------------------------------------------------------------
__global__ __launch_bounds__(512) void lstm1_kernel(
    const float* __restrict__ inp, const float* __restrict__ hprev,
    float* __restrict__ c_io, const float* __restrict__ Wi,
    const float* __restrict__ Wh, const float* __restrict__ bih,
    const float* __restrict__ bhh, float* __restrict__ h_out)
{
    __shared__ float h_s[200 * 33];
    __shared__ float x_s[2][100 * 33];
    __shared__ float ps[12][128];
    const int k = blockIdx.y, jt = blockIdx.x, tid = threadIdx.x;
    const int b = tid & 31, jg = (tid >> 5) & 3, kh = tid >> 7;
    const int j = jt * 4 + jg;

    // stage h (read after the kt loop; first __syncthreads covers it)
    for (int idx = tid; idx < 1600; idx += 512) {
        int bb = idx / 50, m4 = idx % 50;
        float4 v = *(const float4*)&hprev[bb * NHID + k * BS + m4 * 4];
        h_s[(m4 * 4 + 0) * 33 + bb] = v.x;
        h_s[(m4 * 4 + 1) * 33 + bb] = v.y;
        h_s[(m4 * 4 + 2) * 33 + bb] = v.z;
        h_s[(m4 * 4 + 3) * 33 + bb] = v.w;
    }
    // stage x tile 0
    for (int idx = tid; idx < 800; idx += 512) {
        int bb = idx / 25, m4 = idx % 25;
        float4 v = *(const float4*)&inp[(long)(bb * 6 + k) * NINP + m4 * 4];
        x_s[0][(m4 * 4 + 0) * 33 + bb] = v.x;
        x_s[0][(m4 * 4 + 1) * 33 + bb] = v.y;
        x_s[0][(m4 * 4 + 2) * 33 + bb] = v.z;
        x_s[0][(m4 * 4 + 3) * 33 + bb] = v.w;
    }

    const float* wi0 = Wi + (long)(k * 800 + j) * NINP;
    const float* wi1 = wi0 + (long)200 * NINP;
    const float* wi2 = wi0 + (long)400 * NINP;
    const float* wi3 = wi0 + (long)600 * NINP;
    float a0 = 0, a1 = 0, a2 = 0, a3 = 0;
    int cur = 0;
    for (int ti = 0; ti < 24; ti++) {
        __syncthreads();
        if (ti + 1 < 24) {
            int kt = (ti + 1) * 100;
            float* xs = x_s[cur ^ 1];
            for (int idx = tid; idx < 800; idx += 512) {
                int bb = idx / 25, m4 = idx % 25;
                float4 v = *(const float4*)&inp[(long)(bb * 6 + k) * NINP + kt + m4 * 4];
                xs[(m4 * 4 + 0) * 33 + bb] = v.x;
                xs[(m4 * 4 + 1) * 33 + bb] = v.y;
                xs[(m4 * 4 + 2) * 33 + bb] = v.z;
                xs[(m4 * 4 + 3) * 33 + bb] = v.w;
            }
        }
        if (ti / 6 == kh) {
            const int kt = ti * 100;
            const float* xs = x_s[cur];
            for (int m = 0; m < 100; m += 4) {
                float4 w0 = *(const float4*)&wi0[kt + m];
                float4 w1 = *(const float4*)&wi1[kt + m];
                float4 w2 = *(const float4*)&wi2[kt + m];
                float4 w3 = *(const float4*)&wi3[kt + m];
                float x0 = xs[(m + 0) * 33 + b];
                float x1 = xs[(m + 1) * 33 + b];
                float x2 = xs[(m + 2) * 33 + b];
                float x3 = xs[(m + 3) * 33 + b];
                a0 += x0 * w0.x + x1 * w0.y + x2 * w0.z + x3 * w0.w;
                a1 += x0 * w1.x + x1 * w1.y + x2 * w1.z + x3 * w1.w;
                a2 += x0 * w2.x + x1 * w2.y + x2 * w2.z + x3 * w2.w;
                a3 += x0 * w3.x + x1 * w3.y + x2 * w3.z + x3 * w3.w;
            }
        }
        cur ^= 1;
    }
    // Wh part by kh==0 group only (h_s staged at start, covered by syncs)
    if (kh == 0) {
        const float* w0 = Wh + (long)(k * 800 + j) * 200;
        const float* w1 = w0 + 200 * 200;
        const float* w2 = w0 + 400 * 200;
        const float* w3 = w0 + 600 * 200;
        for (int m = 0; m < 200; m += 4) {
            float4 wv0 = *(const float4*)&w0[m];
            float4 wv1 = *(const float4*)&w1[m];
            float4 wv2 = *(const float4*)&w2[m];
            float4 wv3 = *(const float4*)&w3[m];
            float h0v = h_s[(m + 0) * 33 + b];
            float h1v = h_s[(m + 1) * 33 + b];
            float h2v = h_s[(m + 2) * 33 + b];
            float h3v = h_s[(m + 3) * 33 + b];
            a0 += h0v * wv0.x + h1v * wv0.y + h2v * wv0.z + h3v * wv0.w;
            a1 += h0v * wv1.x + h1v * wv1.y + h2v * wv1.z + h3v * wv1.w;
            a2 += h0v * wv2.x + h1v * wv2.y + h2v * wv2.z + h3v * wv2.w;
            a3 += h0v * wv3.x + h1v * wv3.y + h2v * wv3.z + h3v * wv3.w;
        }
    } else {
        int g = (kh - 1) * 4, t = tid & 127;
        ps[g + 0][t] = a0; ps[g + 1][t] = a1; ps[g + 2][t] = a2; ps[g + 3][t] = a3;
    }
    __syncthreads();
    if (kh == 0) {
        a0 += ps[0][tid] + ps[4][tid] + ps[8][tid];
        a1 += ps[1][tid] + ps[5][tid] + ps[9][tid];
        a2 += ps[2][tid] + ps[6][tid] + ps[10][tid];
        a3 += ps[3][tid] + ps[7][tid] + ps[11][tid];
        int nb = k * 800;
        float gi = a0 + bih[nb + j] + bhh[nb + j];
        float gf = a1 + bih[nb + 200 + j] + bhh[nb + 200 + j];
        float gg = a2 + bih[nb + 400 + j] + bhh[nb + 400 + j];
        float go = a3 + bih[nb + 600 + j] + bhh[nb + 600 + j];
        int o = b * NHID + k * BS + j;
        float cold = c_io[o];
        float cn = sigmoidf_(gf) * cold + sigmoidf_(gi) * tanhf(gg);
        float hn = sigmoidf_(go) * tanhf(cn);
        c_io[o] = cn;
        h_out[o] = hn;
    }
}

// ---------------------------------------------------------------------------
// Small self-attention (nh=4, dk=dv=16) + residual + LN over 200. grid=32 (b)
// Weight reads de-duplicated: one global load per weight element.
// ---------------------------------------------------------------------------
__global__ __launch_bounds__(256) void att_small_kernel(
    const float* __restrict__ h_in, float* __restrict__ h_out,
    const float* __restrict__ mq, const float* __restrict__ mk,
    const float* __restrict__ mv, const float* __restrict__ mfc,
    const float* __restrict__ mg, const float* __restrict__ mb)
{
    __shared__ float hb[1200];
    __shared__ float qh[384], kh[384], vh[384];
    __shared__ float att[144];
    __shared__ float outp[384];
    __shared__ float o2[1200];
    __shared__ float mu_s[6], rs_s[6];
    const int b = blockIdx.x, tid = threadIdx.x;
    for (int i = tid; i < 300; i += 256)
        ((float4*)hb)[i] = ((const float4*)(h_in + b * NHID))[i];
    __syncthreads();
    // qkv: which-group per wave; each thread owns (which, hd) and all 6 l's
    if (tid < 192) {
        int which = tid >> 6, hd = tid & 63;
        const float* Mw = which == 0 ? mq : (which == 1 ? mk : mv);
        float acc[6] = {};
        for (int jx = 0; jx < 200; jx++) {
            float w = Mw[jx * 64 + hd];
            #pragma unroll
            for (int l = 0; l < 6; l++) acc[l] += hb[l * 200 + jx] * w;
        }
        float* dst = which == 0 ? qh : (which == 1 ? kh : vh);
        #pragma unroll
        for (int l = 0; l < 6; l++) dst[l * 64 + hd] = acc[l];
    }
    __syncthreads();
    if (tid < 144) {
        int h = tid / 36, r = tid % 36, q = r / 6, kk = r % 6;
        float s = 0;
        #pragma unroll
        for (int d = 0; d < 16; d++) s += qh[q * 64 + h * 16 + d] * kh[kk * 64 + h * 16 + d];
        att[(h * 6 + q) * 6 + kk] = s * 0.25f;  // 1/sqrt(16)
    }
    __syncthreads();
    if (tid < 24) {
        float* a = &att[tid * 6];
        float mx = a[0];
        for (int i = 1; i < 6; i++) mx = fmaxf(mx, a[i]);
        float sm = 0;
        for (int i = 0; i < 6; i++) { a[i] = expf(a[i] - mx); sm += a[i]; }
        float inv = 1.f / sm;
        for (int i = 0; i < 6; i++) a[i] *= inv;
    }
    __syncthreads();
    for (int id = tid; id < 384; id += 256) {
        int q = id >> 6, hd = id & 63, h = hd >> 4;
        float s = 0;
        #pragma unroll
        for (int kk = 0; kk < 6; kk++) s += att[(h * 6 + q) * 6 + kk] * vh[kk * 64 + hd];
        outp[id] = s;
    }
    __syncthreads();
    // FC: thread jx owns all 6 q's; mfc read once per element
    if (tid < 200) {
        float acc[6] = {};
        for (int d = 0; d < 64; d++) {
            float w = mfc[d * 200 + tid];
            #pragma unroll
            for (int q = 0; q < 6; q++) acc[q] += outp[q * 64 + d] * w;
        }
        #pragma unroll
        for (int q = 0; q < 6; q++) o2[q * 200 + tid] = acc[q] + hb[q * 200 + tid];
    }
    __syncthreads();
    if (tid < 6) {
        const float4* o4 = (const float4*)(o2 + tid * 200);
        float s = 0, s2 = 0;
        for (int i = 0; i < 50; i++) {
            float4 v = o4[i];
            s += v.x + v.y + v.z + v.w;
            s2 += v.x * v.x + v.y * v.y + v.z * v.z + v.w * v.w;
        }
        float mu = s / 200.f;
        float var = s2 / 200.f - mu * mu;
        mu_s[tid] = mu;
        rs_s[tid] = 1.0f / sqrtf(var + 1e-5f);
    }
    __syncthreads();
    for (int i = tid; i < 300; i += 256) {
        int q = i / 50;
        float4 v = ((float4*)o2)[i];
        float4 g4 = ((const float4*)mg)[i % 50];
        float4 b4 = ((const float4*)mb)[i % 50];
        float mu = mu_s[q], rstd = rs_s[q];
        float4 r;
        r.x = (v.x - mu) * rstd * g4.x + b4.x;
        r.y = (v.y - mu) * rstd * g4.y + b4.y;
        r.z = (v.z - mu) * rstd * g4.z + b4.z;
        r.w = (v.w - mu) * rstd * g4.w + b4.w;
        ((float4*)(h_out + b * NHID))[i] = r;
    }
}

// ---------------------------------------------------------------------------
// Layer-1 attention via Gram trick: scores[h,q,k] = sum_c h[q,c]*KM[k,h*200+c]
// then softmax and att@V. grid=32 (b).
// ---------------------------------------------------------------------------
__global__ __launch_bounds__(256) void att1_kernel(
    const float* __restrict__ hp,  // (32,1200) query source (h state)
    const float* __restrict__ KM,  // (192,1600) rows (b*6+k) for this t
    const float* __restrict__ VH,
    float* __restrict__ attV)      // (192,1600)
{
    __shared__ float att[288];
    const int b = blockIdx.x, tid = threadIdx.x;
    const float* qb = hp + b * NHID;
    const float* kb = KM + b * 9600;
    const float* vb = VH + b * 9600;
    for (int id = tid; id < 288; id += 256) {
        int h = id / 36, r = id % 36, q = r / 6, kk = r % 6;
        const float4* qr = (const float4*)(qb + q * 200);
        const float4* kr = (const float4*)(kb + kk * L1D + h * 200);
        float s0 = 0, s1 = 0, s2 = 0, s3 = 0;
        #pragma unroll 5
        for (int d = 0; d < 50; d++) {
            float4 a = qr[d], v = kr[d];
            s0 += a.x * v.x; s1 += a.y * v.y; s2 += a.z * v.z; s3 += a.w * v.w;
        }
        att[(h * 6 + q) * 6 + kk] = (s0 + s1 + s2 + s3) * 0.07071067811865475f;  // 1/sqrt(200)
    }
    __syncthreads();
    if (tid < 48) {
        float* a = &att[tid * 6];
        float mx = a[0];
        for (int i = 1; i < 6; i++) mx = fmaxf(mx, a[i]);
        float sm = 0;
        for (int i = 0; i < 6; i++) { a[i] = expf(a[i] - mx); sm += a[i]; }
        float inv = 1.f / sm;
        for (int i = 0; i < 6; i++) a[i] *= inv;
    }
    __syncthreads();
    for (int hd = tid; hd < L1D; hd += 256) {
        int h = hd / 200;
        float v0 = vb[0 * L1D + hd], v1 = vb[1 * L1D + hd], v2 = vb[2 * L1D + hd];
        float v3 = vb[3 * L1D + hd], v4 = vb[4 * L1D + hd], v5 = vb[5 * L1D + hd];
        #pragma unroll
        for (int q = 0; q < 6; q++) {
            const float* a = &att[(h * 6 + q) * 6];
            float s = a[0] * v0 + a[1] * v1 + a[2] * v2 + a[3] * v3 + a[4] * v4 + a[5] * v5;
            attV[b * 9600 + q * L1D + hd] = s;
        }
    }
}

// ---------------------------------------------------------------------------
// Sum 4 split-K partials + LayerNorm over 2400. grid = 192 rows, 256 thr.
// ---------------------------------------------------------------------------
__global__ __launch_bounds__(256) void ln_sum4_kernel(
    const float* __restrict__ Fp, float* __restrict__ Y,
    const float* __restrict__ g, const float* __restrict__ bta)
{
    __shared__ float rowbuf[2400];
    __shared__ float aw[4], bw[4];
    const int r = blockIdx.x, tid = threadIdx.x;
    const long SL = (long)192 * NINP / 4;
    const float4* f0 = (const float4*)(Fp) + (long)r * (NINP / 4);
    float s = 0, s2 = 0;
    for (int i = tid; i < 600; i += 256) {
        float4 a = f0[i], b2 = f0[SL + i], c = f0[2 * SL + i], d = f0[3 * SL + i];
        float4 v;
        v.x = a.x + b2.x + c.x + d.x;
        v.y = a.y + b2.y + c.y + d.y;
        v.z = a.z + b2.z + c.z + d.z;
        v.w = a.w + b2.w + c.w + d.w;
        ((float4*)rowbuf)[i] = v;
        s += v.x + v.y + v.z + v.w;
        s2 += v.x * v.x + v.y * v.y + v.z * v.z + v.w * v.w;
    }
    for (int off = 32; off; off >>= 1) { s += __shfl_down(s, off); s2 += __shfl_down(s2, off); }
    int wid = tid >> 6, lane = tid & 63;
    if (lane == 0) { aw[wid] = s; bw[wid] = s2; }
    __syncthreads();
    if (tid == 0) {
        float a = 0, a2 = 0;
        for (int w = 0; w < 4; w++) { a += aw[w]; a2 += bw[w]; }
        float mu = a / NINP;
        float var = a2 / NINP - mu * mu;
        aw[0] = mu;
        bw[0] = 1.0f / sqrtf(var + 1e-5f);
    }
    __syncthreads();
    float mu = aw[0], rstd = bw[0];
    for (int i = tid; i < 600; i += 256) {
        float4 v = ((float4*)rowbuf)[i];
        float4 g4 = ((const float4*)g)[i];
        float4 b4 = ((const float4*)bta)[i];
        float4 o;
        o.x = (v.x - mu) * rstd * g4.x + b4.x;
        o.y = (v.y - mu) * rstd * g4.y + b4.y;
        o.z = (v.z - mu) * rstd * g4.z + b4.z;
        o.w = (v.w - mu) * rstd * g4.w + b4.w;
        ((float4*)(Y + (long)r * NINP))[i] = o;
    }
}

// ---------------------------------------------------------------------------
extern "C" void kernel_launch(void* const* d_in, const int* in_sizes, int n_in,
                              void* d_out, int out_size, void* d_ws, size_t ws_size,
                              hipStream_t stream)
{
    const int*   tokens = (const int*)  d_in[0];
    const float* h0     = (const float*)d_in[1];
    const float* c0     = (const float*)d_in[2];
    const float* emb    = (const float*)d_in[3];
    const float* Wi     = (const float*)d_in[4];
    const float* Wh     = (const float*)d_in[5];
    const float* bih    = (const float*)d_in[6];
    const float* bhh    = (const float*)d_in[7];
    const float* mq     = (const float*)d_in[8];
    const float* mk     = (const float*)d_in[9];
    const float* mv     = (const float*)d_in[10];
    const float* mfc    = (const float*)d_in[11];
    const float* mg     = (const float*)d_in[12];
    const float* mb     = (const float*)d_in[13];
    const float* lq     = (const float*)d_in[14];
    const float* lk     = (const float*)d_in[15];
    const float* lv     = (const float*)d_in[16];
    const float* lfc    = (const float*)d_in[17];
    const float* lg     = (const float*)d_in[18];
    const float* lb     = (const float*)d_in[19];
    const float* dec_w  = (const float*)d_in[20];
    const float* dec_b  = (const float*)d_in[21];
    float* out = (float*)d_out;

    // workspace carve-up (floats)
    float* p = (float*)d_ws;
    float* GX0  = p; p += (long)ROWS * NG;        // 1024*4800
    float* out0 = p; p += (long)ROWS * NHID;      // 1024*1200
    float* out1 = p; p += (long)ROWS * NHID;
    float* KM   = p; p += (long)ROWS * 6 * L1D;   // 6144*1600
    float* VH1  = p; p += (long)ROWS * 6 * L1D;
    float* attV = p; p += 192 * L1D;
    float* FCp  = p; p += (long)4 * 192 * NINP;   // split-K partials
    float* inp  = p; p += 192 * NINP;
    float* htmp = p; p += BZ * NHID;
    float* cb0  = p; p += BZ * NHID;
    float* cb1  = p; p += BZ * NHID;
    float* BigB = p; p += 200 * L1D;

    const int ST = BZ * NHID;  // 38400 floats per (32,1200) state

    hipMemcpyAsync(cb0, c0,      ST * sizeof(float), hipMemcpyDeviceToDevice, stream);
    hipMemcpyAsync(cb1, c0 + ST, ST * sizeof(float), hipMemcpyDeviceToDevice, stream);

    // BigB = per-head Gram lq_h @ lk_h^T, laid out (200 x 1600)
    bigb_kernel<<<1250, 256, 0, stream>>>(lq, lk, BigB);

    // GX0 = emb[tokens] @ Wi^T + bih + bhh
    gemm128_kernel<true><<<dim3(NG / 128 + 1, ROWS / 128), 256, 0, stream>>>(
        emb, Wi, bih, bhh, GX0, ROWS, NG, NINP, tokens);

    // ---- Phase A: layer-0 scan ----
    for (int t = 0; t < TT; t++) {
        const float* hp = (t == 0) ? h0 : out0 + (t - 1) * ST;
        lstm0_kernel<<<dim3(25, 6), 256, 0, stream>>>(
            GX0 + (long)t * BZ * NG, hp, cb0, Wh, htmp);
        att_small_kernel<<<BZ, 256, 0, stream>>>(htmp, out0 + t * ST, mq, mk, mv, mfc, mg, mb);
    }

    // KM = out0 @ BigB (Gram-projected keys), VH1 = out0 @ lv
    gemm128_kernel<false><<<dim3((L1D + 127) / 128, (ROWS * 6) / 128), 256, 0, stream>>>(
        out0, BigB, nullptr, nullptr, KM, ROWS * 6, L1D, BS, nullptr);
    gemm128_kernel<false><<<dim3((L1D + 127) / 128, (ROWS * 6) / 128), 256, 0, stream>>>(
        out0, lv, nullptr, nullptr, VH1, ROWS * 6, L1D, BS, nullptr);

    // ---- Phase B: layer-1 scan ----
    for (int t = 0; t < TT; t++) {
        const float* hp = (t == 0) ? h0 + ST : out1 + (t - 1) * ST;
        att1_kernel<<<BZ, 256, 0, stream>>>(
            hp, KM + (long)t * BZ * 6 * L1D, VH1 + (long)t * BZ * 6 * L1D, attV);
        // F partials = attV @ lfc  (192,2400 K=1600, split-K 4)
        gemm_skp_kernel<<<dim3((NINP + 63) / 64, 3, 4), 256, 0, stream>>>(
            attV, lfc, FCp, 192, NINP, L1D, 400);
        ln_sum4_kernel<<<192, 256, 0, stream>>>(FCp, inp, lg, lb);
        lstm1_kernel<<<dim3(50, 6), 512, 0, stream>>>(inp, hp, cb1, Wi, Wh, bih, bhh, htmp);
        att_small_kernel<<<BZ, 256, 0, stream>>>(htmp, out1 + t * ST, mq, mk, mv, mfc, mg, mb);
    }

    // decode: out1 (1024,1200) @ dec_w^T + dec_b -> d_out (1024,16000)
    gemm128_kernel<true><<<dim3(NTOK / 128, ROWS / 128), 256, 0, stream>>>(
        out1, dec_w, dec_b, nullptr, out, ROWS, NTOK, NHID, nullptr);

    // final states: [hf0; hf1] then [cf0; cf1]
    long off = (long)ROWS * NTOK;
    hipMemcpyAsync(out + off,          out0 + 31 * ST, ST * sizeof(float), hipMemcpyDeviceToDevice, stream);
    hipMemcpyAsync(out + off + ST,     out1 + 31 * ST, ST * sizeof(float), hipMemcpyDeviceToDevice, stream);
    hipMemcpyAsync(out + off + 2 * ST, cb0,            ST * sizeof(float), hipMemcpyDeviceToDevice, stream);
    hipMemcpyAsync(out + off + 3 * ST, cb1,            ST * sizeof(float), hipMemcpyDeviceToDevice, stream);
}